// Round 1
// baseline (329.744 us; speedup 1.0000x reference)
//
#include <hip/hip_runtime.h>
#include <float.h>

#define KCODES 512
#define GDIM 64
#define TAU 2.0e-3f   // validated r2-r5 (absmax 0); pass-A err budget here ~3e-4

typedef __attribute__((ext_vector_type(8))) short short8;   // 8 bf16 = 4 VGPR
typedef __attribute__((ext_vector_type(4))) float floatx4;  // MFMA C/D

// ---- workspace layout (float-index units) ----
// embT   f32[512*64]     [0, 32768)
// e2     f32[512]        [32768, 33280)
// e2d    f64[512]        [33280, 34304)  (byte 133120, 8-aligned)
// emb_hi bf16[512*64]    [34304, 50688)  (code-major, 64/row)
// emb_lo bf16[512*64]    [50688, 67072)
// bitmap u32[8192]       [67072, 75264)  (fallback tie-flag path)
// count  u32             75264
// list   u32[262144]     [75280, 337424) (tie worklist; cap == #positions, no overflow)

__device__ __forceinline__ void bf16split(float x, short& hi, short& lo) {
    unsigned u = __float_as_uint(x);
    unsigned h = (u + 0x7fffu + ((u >> 16) & 1u)) >> 16;   // RNE to bf16
    hi = (short)h;
    float hf = __uint_as_float(h << 16);
    float l = x - hf;                                      // exact in f32
    unsigned ul = __float_as_uint(l);
    lo = (short)((ul + 0x7fffu + ((ul >> 16) & 1u)) >> 16);
}

// async 16B global->LDS DMA (linear dest = wave base + lane*16)
__device__ __forceinline__ void gload_lds16(const void* g, void* l) {
    __builtin_amdgcn_global_load_lds(
        (const __attribute__((address_space(1))) void*)g,
        (__attribute__((address_space(3))) void*)l, 16, 0, 0);
}

// grid 128x256 = 32768 threads = 512 waves: wave k preps code k (lane = dim g).
// Old version ran 512 serial threads (2 blocks, 8 waves) -> pure latency chain.
// e2 summation order changes (butterfly vs sequential): delta ~1e-5 << the
// 1.7e-3 margin between pass-A error (3e-4) and TAU; e2d delta ~1e-14, far
// below any real f64 gap between distinct random codes.
__launch_bounds__(256)
__global__ void prep_kernel(const float* __restrict__ w,
                            float* __restrict__ embT,
                            float* __restrict__ e2,
                            double* __restrict__ e2d,
                            short* __restrict__ emb_hi,
                            short* __restrict__ emb_lo,
                            unsigned* __restrict__ bitmap,
                            unsigned* __restrict__ count) {
    int t = blockIdx.x * 256 + threadIdx.x;   // 0..32767
    if (t < 8192) bitmap[t] = 0u;
    if (t == 0) count[0] = 0u;
    int k = t >> 6;                            // code (wave-uniform)
    int g = t & 63;                            // dim  (lane)
    float v = w[(size_t)g * KCODES + k];
    embT[(size_t)k * GDIM + g] = v;            // lane-contiguous store
    short h, l; bf16split(v, h, l);
    emb_hi[(size_t)k * GDIM + g] = h;
    emb_lo[(size_t)k * GDIM + g] = l;
    float s = v * v;
    double sd = (double)v * (double)v;
#pragma unroll
    for (int off = 32; off > 0; off >>= 1) {
        s  += __shfl_xor(s, off, 64);
        sd += __shfl_xor(sd, off, 64);
    }
    if (g == 0) { e2[k] = s; e2d[k] = sd; }
}

// Pass A (MFMA): wave = 32 positions (2 m-tiles); 512 codes in 8 chunks of 64,
// double-buffered via global_load_lds DMA: prefetch of chunk ch+1 issues BEFORE
// the chunk-ch MFMA block and is drained by the single per-chunk barrier, so
// codebook L2 latency hides under ~800cy of compute (old: stage->barrier->
// compute, latency fully exposed).
// LDS layout: pad-free 64-short rows with XOR granule swizzle — logical 8-short
// unit u of row r lives at unit position u^(r&7). gload_lds writes linearly, so
// the swizzle is applied by pre-swizzling the per-lane GLOBAL source address
// (both-sides-or-neither rule). Read of granule q / q+4 for code row r=nt*16+c:
// position (q^(c&7)) / that^4 -> per-16-lane phase start banks 4*(q^p), p=0..7
// each twice = same 2x-start-bank b128 floor as the old 72-short padding.
// dot = hi.hi + hi.lo + lo.hi split-bf16 (err <= ~3e-4 << TAU).
// A-frag: A[m=lane&15][k=quad*8+j]; B[k=quad*8+j][n=lane&15]; C/D: m=quad*4+reg,
// n=lane&15 (all doc-verified, unchanged from the 301us version).
__launch_bounds__(256, 1)
__global__ void vq_kernel(const float* __restrict__ x,
                          const float* __restrict__ embT,
                          const float* __restrict__ e2,
                          const short* __restrict__ emb_hi,
                          const short* __restrict__ emb_lo,
                          float* __restrict__ out_res,
                          float* __restrict__ out_arg,
                          unsigned* __restrict__ bitmap,
                          unsigned* __restrict__ list,
                          unsigned* __restrict__ count,
                          int use_list) {
    __shared__ short s_hi[2][64 * 64];
    __shared__ short s_lo[2][64 * 64];
    __shared__ float s_e2[512];
    __shared__ int   s_arg[128];

    const int t = threadIdx.x;
    const int wid = t >> 6;
    const int lane = t & 63;
    const int q = lane >> 4;          // quad
    const int c = lane & 15;          // col within tile
    const int blk = blockIdx.x;
    const int grp = blk >> 9;                          // 512 blocks per group
    const int posbase = ((blk & 511) << 7) + wid * 32; // wave's 32 positions
    const int b = posbase >> 10;
    const int hwb = posbase & 1023;

    // DMA geometry: wave wid owns LDS shorts [wid*1024, wid*1024+1024)
    // = rows wid*16..wid*16+16.  Instr0 covers rows rA=wid*16+(lane>>3),
    // instr1 rows rB=rA+8 (same low-3 bits -> same swizzled unit uA).
    const int rA = wid * 16 + (lane >> 3);
    const int rB = rA + 8;
    const int uA = (lane & 7) ^ (rA & 7);
    const int srcA = rA * 64 + uA * 8;   // element offset within chunk
    const int srcB = rB * 64 + uA * 8;

#define PREFETCH(CH, BUF)                                                      \
    {                                                                          \
        const short* gh_ = emb_hi + (size_t)(CH) * 4096;                       \
        const short* gl_ = emb_lo + (size_t)(CH) * 4096;                       \
        gload_lds16(gh_ + srcA, &s_hi[BUF][wid * 1024]);                       \
        gload_lds16(gh_ + srcB, &s_hi[BUF][wid * 1024 + 512]);                 \
        gload_lds16(gl_ + srcA, &s_lo[BUF][wid * 1024]);                       \
        gload_lds16(gl_ + srcB, &s_lo[BUF][wid * 1024 + 512]);                 \
    }

    // issue chunk-0 DMA first; A-frag loads below overlap it
    PREFETCH(0, 0);
    s_e2[t] = e2[t];
    s_e2[t + 256] = e2[t + 256];

    const float* xbase = x + (size_t)b * 262144 + (size_t)grp * 65536 + hwb;

    // A fragments: [mt][kt], hi and lo. 8 strided dwords each, split to bf16.
    short8 ahi[2][2], alo[2][2];
#pragma unroll
    for (int mt = 0; mt < 2; ++mt)
#pragma unroll
        for (int kt = 0; kt < 2; ++kt) {
#pragma unroll
            for (int j = 0; j < 8; ++j) {
                float xv = xbase[(kt * 32 + q * 8 + j) * 1024 + mt * 16 + c];
                short h, l; bf16split(xv, h, l);
                ahi[mt][kt][j] = h; alo[mt][kt][j] = l;
            }
        }

    float best[2][4], sec[2][4]; int arg[2][4];
#pragma unroll
    for (int mt = 0; mt < 2; ++mt)
#pragma unroll
        for (int r = 0; r < 4; ++r) { best[mt][r] = FLT_MAX; sec[mt][r] = FLT_MAX; arg[mt][r] = 0; }

    const int p8 = (q ^ (c & 7)) << 3;   // swizzled read granule (shorts)

    __syncthreads();                      // drains chunk-0 DMA + e2 stage

    int cur = 0;
    for (int ch = 0; ch < 8; ++ch) {
        if (ch < 7) PREFETCH(ch + 1, cur ^ 1);   // in flight across MFMA block
        const int C0 = ch * 64;

        floatx4 acc[2][4];
#pragma unroll
        for (int mt = 0; mt < 2; ++mt)
#pragma unroll
            for (int nt = 0; nt < 4; ++nt) acc[mt][nt] = (floatx4){0.f, 0.f, 0.f, 0.f};

#pragma unroll
        for (int nt = 0; nt < 4; ++nt) {
            const int o = (nt * 16 + c) * 64 + p8;     // (r&7)==(c&7) since 16|nt*16
            short8 bh0 = *(const short8*)&s_hi[cur][o];
            short8 bh1 = *(const short8*)&s_hi[cur][o ^ 32];   // granule q+4
            short8 bl0 = *(const short8*)&s_lo[cur][o];
            short8 bl1 = *(const short8*)&s_lo[cur][o ^ 32];
#pragma unroll
            for (int mt = 0; mt < 2; ++mt) {
                floatx4 a4 = acc[mt][nt];
                a4 = __builtin_amdgcn_mfma_f32_16x16x32_bf16(alo[mt][0], bh0, a4, 0, 0, 0);
                a4 = __builtin_amdgcn_mfma_f32_16x16x32_bf16(ahi[mt][0], bl0, a4, 0, 0, 0);
                a4 = __builtin_amdgcn_mfma_f32_16x16x32_bf16(ahi[mt][0], bh0, a4, 0, 0, 0);
                a4 = __builtin_amdgcn_mfma_f32_16x16x32_bf16(alo[mt][1], bh1, a4, 0, 0, 0);
                a4 = __builtin_amdgcn_mfma_f32_16x16x32_bf16(ahi[mt][1], bl1, a4, 0, 0, 0);
                a4 = __builtin_amdgcn_mfma_f32_16x16x32_bf16(ahi[mt][1], bh1, a4, 0, 0, 0);
                acc[mt][nt] = a4;
            }
        }

        // chunk epilogue: s = e2 - 2*dot, running (best, sec, arg) per m-slot
#pragma unroll
        for (int mt = 0; mt < 2; ++mt)
#pragma unroll
            for (int nt = 0; nt < 4; ++nt) {
                float se2 = s_e2[C0 + nt * 16 + c];
                int n = C0 + nt * 16 + c;
#pragma unroll
                for (int r = 0; r < 4; ++r) {
                    float s = __fmaf_rn(-2.0f, acc[mt][nt][r], se2);
                    if (s < best[mt][r]) { sec[mt][r] = best[mt][r]; best[mt][r] = s; arg[mt][r] = n; }
                    else if (s < sec[mt][r]) sec[mt][r] = s;
                }
            }

        // single barrier/chunk: separates this chunk's reads of buf[cur] from
        // next iter's DMA into buf[cur], and completes DMA into buf[cur^1].
        __syncthreads();
        cur ^= 1;
    }

    // cross-lane merge over the 16 cols (ties -> gap<=TAU -> flagged -> f64 fix)
#pragma unroll
    for (int mt = 0; mt < 2; ++mt)
#pragma unroll
        for (int r = 0; r < 4; ++r) {
            float b_ = best[mt][r], s_ = sec[mt][r]; int a_ = arg[mt][r];
#pragma unroll
            for (int sh = 1; sh < 16; sh <<= 1) {
                float ob = __shfl_xor(b_, sh, 64);
                float os = __shfl_xor(s_, sh, 64);
                int   oa = __shfl_xor(a_, sh, 64);
                if (ob < b_) { s_ = fminf(b_, os); b_ = ob; a_ = oa; }
                else         { s_ = fminf(s_, ob); }
            }
            if (c == 0) {
                int p = mt * 16 + q * 4 + r;          // 0..31 within wave
                s_arg[wid * 32 + p] = a_;
                if (s_ - b_ <= TAU) {
                    int gidx = grp * 65536 + posbase + p;
                    if (use_list) {
                        unsigned slot = atomicAdd(count, 1u);
                        list[slot] = (unsigned)gidx;
                    } else {
                        atomicOr(&bitmap[gidx >> 5], 1u << (gidx & 31));
                    }
                }
            }
        }
    __syncthreads();

    // argmin output: block's 128 positions, one coalesced pass
    if (t < 128) {
        int bp = ((blk & 511) << 7) + t;
        out_arg[(size_t)(bp >> 10) * 4096 + (size_t)grp * 1024 + (bp & 1023)] =
            (float)s_arg[t];
    }

    // result output: wave's 32 positions, lane = (gi, p), stores 2x128B runs
    {
        int p = lane & 31, gi = lane >> 5;
        int ac = s_arg[wid * 32 + p];
        const float* ev = embT + (size_t)ac * GDIM;
        float* rp = out_res + (size_t)b * 262144 + (size_t)grp * 65536 + hwb + p;
#pragma unroll
        for (int it = 0; it < 32; ++it) {
            int g = it * 2 + gi;
            rp[(size_t)g * 1024] = ev[g] * 0.5f;
        }
    }
#undef PREFETCH
}

// Pass B: exact f64 re-rank of flagged positions. Rank by s = e2d[k] - 2*dot
// (the per-position |x|^2 shift is rank-irrelevant).
__device__ __forceinline__ void fix_pos(int gidx, const float* __restrict__ x,
                                        const float* __restrict__ embT,
                                        const double* __restrict__ e2d,
                                        float* __restrict__ out_res,
                                        float* __restrict__ out_arg, int lane) {
    const int grp = gidx >> 16;
    const int pos = gidx & 65535;
    const int b = pos >> 10;
    const int sidx = pos & 1023;

    const float* xp = x + (size_t)b * 262144 + (size_t)grp * 65536 + sidx;
    float xr[GDIM];
#pragma unroll
    for (int g = 0; g < GDIM; ++g) xr[g] = xp[g * 1024];

    double bd = DBL_MAX;
    int bk = 0;
    for (int m = 0; m < KCODES / 64; ++m) {
        const int k = lane + m * 64;
        const float* er = embT + (size_t)k * GDIM;
        double dot = 0.0;
#pragma unroll
        for (int g = 0; g < GDIM; g += 4) {
            float4 e4 = *(const float4*)(er + g);
            dot += (double)xr[g + 0] * (double)e4.x;
            dot += (double)xr[g + 1] * (double)e4.y;
            dot += (double)xr[g + 2] * (double)e4.z;
            dot += (double)xr[g + 3] * (double)e4.w;
        }
        double s = e2d[k] - 2.0 * dot;
        if (s < bd) { bd = s; bk = k; }            // ascending k per lane
    }
    for (int off = 32; off > 0; off >>= 1) {       // lexicographic (s, k)
        double od = __shfl_down(bd, off, 64);
        int    ok = __shfl_down(bk, off, 64);
        if (od < bd || (od == bd && ok < bk)) { bd = od; bk = ok; }
    }
    bk = __shfl(bk, 0, 64);

    if (lane == 0)
        out_arg[(size_t)b * 4096 + (size_t)grp * 1024 + sidx] = (float)bk;
    out_res[(size_t)b * 262144 + (size_t)grp * 65536 + (size_t)lane * 1024 + sidx] =
        embT[(size_t)bk * GDIM + lane] * 0.5f;
}

__launch_bounds__(256)
__global__ void fix_kernel(const float* __restrict__ x,
                           const float* __restrict__ embT,
                           const double* __restrict__ e2d,
                           const unsigned* __restrict__ bitmap,
                           const unsigned* __restrict__ list,
                           const unsigned* __restrict__ count,
                           int use_list,
                           float* __restrict__ out_res,
                           float* __restrict__ out_arg) {
    const int lane = threadIdx.x & 63;
    const int wave = (blockIdx.x * blockDim.x + threadIdx.x) >> 6;
    const int nwaves = (gridDim.x * blockDim.x) >> 6;

    if (use_list) {
        // compact worklist: ~hundreds of entries vs 262144-bit bitmap scan
        const unsigned n = count[0];
        for (unsigned i = (unsigned)wave; i < n; i += (unsigned)nwaves)
            fix_pos((int)list[i], x, embT, e2d, out_res, out_arg, lane);
    } else {
        for (int gidx = wave; gidx < 262144; gidx += nwaves) {
            if (!((bitmap[gidx >> 5] >> (gidx & 31)) & 1u)) continue;
            fix_pos(gidx, x, embT, e2d, out_res, out_arg, lane);
        }
    }
}

extern "C" void kernel_launch(void* const* d_in, const int* in_sizes, int n_in,
                              void* d_out, int out_size, void* d_ws, size_t ws_size,
                              hipStream_t stream) {
    const float* x = (const float*)d_in[0];      // (64,256,32,32) f32
    const float* w = (const float*)d_in[1];      // (64,512) f32
    float* out_res = (float*)d_out;              // 16777216 floats
    float* out_arg = (float*)d_out + 16777216;   // 262144 floats

    float*    embT   = (float*)d_ws;
    float*    e2     = embT + 32768;
    double*   e2d    = (double*)((char*)d_ws + (size_t)33280 * 4);
    short*    emb_hi = (short*)((float*)d_ws + 34304);
    short*    emb_lo = (short*)((float*)d_ws + 50688);
    unsigned* bitmap = (unsigned*)((float*)d_ws + 67072);
    unsigned* count  = (unsigned*)((float*)d_ws + 75264);
    unsigned* list   = (unsigned*)((float*)d_ws + 75280);

    // worklist needs (75280 + 262144)*4 B; fall back to bitmap scan otherwise
    const int use_list = (ws_size >= (size_t)(75280 + 262144) * 4) ? 1 : 0;

    prep_kernel<<<128, 256, 0, stream>>>(w, embT, e2, e2d, emb_hi, emb_lo,
                                         bitmap, count);
    vq_kernel<<<2048, 256, 0, stream>>>(x, embT, e2, emb_hi, emb_lo,
                                        out_res, out_arg, bitmap, list, count,
                                        use_list);
    fix_kernel<<<1024, 256, 0, stream>>>(x, embT, e2d, bitmap, list, count,
                                         use_list, out_res, out_arg);
}

// Round 2
// 248.584 us; speedup vs baseline: 1.3265x; 1.3265x over previous
//
#include <hip/hip_runtime.h>
#include <float.h>

#define KCODES 512
#define GDIM 64
#define TAU 4.0e-3f   // pass-A worst err ~1e-3 (split-bf16, -2-folded); flags ~800 total, exact f64 fix

typedef __attribute__((ext_vector_type(8))) short short8;   // 8 bf16 = 4 VGPR
typedef __attribute__((ext_vector_type(4))) float floatx4;  // MFMA C/D

// ---- workspace layout (float-index units) ----
// embT   f32[512*64]     [0, 32768)        original w, code-major
// e2     f32[512]        [32768, 33280)
// e2d    f64[512]        [33280, 34304)    (byte 133120, 8-aligned)
// emb_hi bf16[512*64]    [34304, 50688)    split of (-2*w), code-major
// emb_lo bf16[512*64]    [50688, 67072)

__device__ __forceinline__ void bf16split(float x, short& hi, short& lo) {
    unsigned u = __float_as_uint(x);
    unsigned h = (u + 0x7fffu + ((u >> 16) & 1u)) >> 16;   // RNE to bf16
    hi = (short)h;
    float hf = __uint_as_float(h << 16);
    float l = x - hf;                                      // exact in f32
    unsigned ul = __float_as_uint(l);
    lo = (short)((ul + 0x7fffu + ((ul >> 16) & 1u)) >> 16);
}

__device__ __forceinline__ void gload_lds16(const void* g, void* l) {
    __builtin_amdgcn_global_load_lds(
        (const __attribute__((address_space(1))) void*)g,
        (__attribute__((address_space(3))) void*)l, 16, 0, 0);
}

// 128 blocks x 256 = 512 waves: wave k preps code k (lane = dim g).
// emb_hi/lo now store split of (-2*w): exact x(-2) scaling, folds the -2 into
// the MFMA so the epilogue has no per-candidate fma (C is preloaded with e2).
__launch_bounds__(256)
__global__ void prep_kernel(const float* __restrict__ w,
                            float* __restrict__ embT,
                            float* __restrict__ e2,
                            double* __restrict__ e2d,
                            short* __restrict__ emb_hi,
                            short* __restrict__ emb_lo) {
    int t = blockIdx.x * 256 + threadIdx.x;   // 0..32767
    int k = t >> 6;                            // code (wave-uniform)
    int g = t & 63;                            // dim  (lane)
    float v = w[(size_t)g * KCODES + k];
    embT[(size_t)k * GDIM + g] = v;            // lane-contiguous store
    short h, l; bf16split(-2.0f * v, h, l);
    emb_hi[(size_t)k * GDIM + g] = h;
    emb_lo[(size_t)k * GDIM + g] = l;
    float s = v * v;
    double sd = (double)v * (double)v;
#pragma unroll
    for (int off = 32; off > 0; off >>= 1) {
        s  += __shfl_xor(s, off, 64);
        sd += __shfl_xor(sd, off, 64);
    }
    if (g == 0) { e2[k] = s; e2d[k] = sd; }
}

// Fused pass A + exact fix. 512 blocks x 1024 threads (16 waves, 1 block/CU).
// Block owns one (grp, b, half) slice of 512 positions; wave = 32 positions.
// ENTIRE codebook (512 codes, hi+lo, XOR-granule-swizzled via pre-swizzled
// global source) staged once -> main loop is barrier-free.
// acc preloaded with e2 (C-operand), codebook holds -2w  =>  s = acc directly.
// best/sec: min + fmed3 (median{best_old, sec, s} == new second-min).
// Near-ties (sec-best<=TAU) recorded in LDS; block tail reranks them in f64
// (lexicographic (s,k)) and overwrites out_arg/out_res — no third kernel.
__launch_bounds__(1024, 4)
__global__ void vq_kernel(const float* __restrict__ x,
                          const float* __restrict__ embT,
                          const float* __restrict__ e2,
                          const double* __restrict__ e2d,
                          const short* __restrict__ emb_hi,
                          const short* __restrict__ emb_lo,
                          float* __restrict__ out_res,
                          float* __restrict__ out_arg) {
    __shared__ short s_hi[512 * 64];
    __shared__ short s_lo[512 * 64];
    __shared__ float s_e2[512];
    __shared__ int   s_arg[512];
    __shared__ float s_fixx[16][64];
    __shared__ int   s_flags[512];
    __shared__ int   s_nflag;

    const int t = threadIdx.x;
    const int wid = t >> 6;
    const int lane = t & 63;
    const int q = lane >> 4;          // quad
    const int c = lane & 15;          // col within tile
    const int blk = blockIdx.x;
    const int grp = blk >> 7;                 // 128 blocks per group
    const int rem = blk & 127;
    const int b = rem >> 1;                   // batch
    const int half = rem & 1;
    const int hw0 = half * 512 + wid * 32;    // wave's 32 positions (abs in slice)

    if (t == 0) s_nflag = 0;

    // ---- stage full codebook, swizzled: LDS(row R, pos p) = emb(R, p^(R&7)).
    // DMA dest is linear (wave base + lane*16B); swizzle applied on SOURCE.
#pragma unroll
    for (int i = 0; i < 4; ++i) {
        int r = i * 16 + wid;                      // 64 regions of 8 rows
        int srcRow = r * 8 + (lane >> 3);
        int srcOff = srcRow * 64 + (((lane & 7) ^ (lane >> 3)) << 3);
        gload_lds16(emb_hi + srcOff, &s_hi[r * 512]);
        gload_lds16(emb_lo + srcOff, &s_lo[r * 512]);
    }
    if (t < 512) s_e2[t] = e2[t];

    // ---- A fragments (overlap the DMA): [mt][kt], hi and lo
    const float* xbase = x + (size_t)b * 262144 + (size_t)grp * 65536 + hw0;
    short8 ahi[2][2], alo[2][2];
#pragma unroll
    for (int mt = 0; mt < 2; ++mt)
#pragma unroll
        for (int kt = 0; kt < 2; ++kt) {
#pragma unroll
            for (int j = 0; j < 8; ++j) {
                float xv = xbase[(kt * 32 + q * 8 + j) * 1024 + mt * 16 + c];
                short h, l; bf16split(xv, h, l);
                ahi[mt][kt][j] = h; alo[mt][kt][j] = l;
            }
        }

    float best[2][4], sec[2][4]; int arg[2][4];
#pragma unroll
    for (int mt = 0; mt < 2; ++mt)
#pragma unroll
        for (int r = 0; r < 4; ++r) { best[mt][r] = FLT_MAX; sec[mt][r] = FLT_MAX; arg[mt][r] = 0; }

    const int obase = c * 64 + ((q ^ (c & 7)) << 3);   // swizzled read granule

    __syncthreads();   // codebook + e2 resident; NO further barriers in main loop

#pragma unroll 4
    for (int nt = 0; nt < 32; ++nt) {
        const int o = nt * 1024 + obase;               // row nt*16+c, granule q
        short8 bh0 = *(const short8*)&s_hi[o];
        short8 bh1 = *(const short8*)&s_hi[o ^ 32];    // granule q+4
        short8 bl0 = *(const short8*)&s_lo[o];
        short8 bl1 = *(const short8*)&s_lo[o ^ 32];
        float se2 = s_e2[nt * 16 + c];
#pragma unroll
        for (int mt = 0; mt < 2; ++mt) {
            floatx4 a4 = (floatx4){se2, se2, se2, se2};   // C = e2 (codebook = -2w)
            a4 = __builtin_amdgcn_mfma_f32_16x16x32_bf16(alo[mt][0], bh0, a4, 0, 0, 0);
            a4 = __builtin_amdgcn_mfma_f32_16x16x32_bf16(ahi[mt][0], bl0, a4, 0, 0, 0);
            a4 = __builtin_amdgcn_mfma_f32_16x16x32_bf16(ahi[mt][0], bh0, a4, 0, 0, 0);
            a4 = __builtin_amdgcn_mfma_f32_16x16x32_bf16(alo[mt][1], bh1, a4, 0, 0, 0);
            a4 = __builtin_amdgcn_mfma_f32_16x16x32_bf16(ahi[mt][1], bl1, a4, 0, 0, 0);
            a4 = __builtin_amdgcn_mfma_f32_16x16x32_bf16(ahi[mt][1], bh1, a4, 0, 0, 0);
            // epilogue: s = a4[r] directly; 4 VALU per candidate
#pragma unroll
            for (int r = 0; r < 4; ++r) {
                float s = a4[r];
                float bo = best[mt][r];
                best[mt][r] = fminf(bo, s);
                arg[mt][r]  = (s < bo) ? nt : arg[mt][r];
                sec[mt][r]  = __builtin_amdgcn_fmed3f(bo, sec[mt][r], s);
            }
        }
    }

    // ---- cross-lane merge over the 16 cols; record args + near-tie flags
#pragma unroll
    for (int mt = 0; mt < 2; ++mt)
#pragma unroll
        for (int r = 0; r < 4; ++r) {
            float b_ = best[mt][r], s_ = sec[mt][r];
            int n_ = arg[mt][r] * 16 + c;              // full code index
#pragma unroll
            for (int sh = 1; sh < 16; sh <<= 1) {
                float ob = __shfl_xor(b_, sh, 64);
                float os = __shfl_xor(s_, sh, 64);
                int   on = __shfl_xor(n_, sh, 64);
                float bo = b_;
                b_ = fminf(bo, ob);
                n_ = (ob < bo) ? on : n_;
                s_ = fminf(fminf(s_, os), fmaxf(bo, ob));   // 2nd-min of union
            }
            if (c == 0) {
                int p = mt * 16 + q * 4 + r;           // 0..31 within wave
                s_arg[wid * 32 + p] = n_;
                if (s_ - b_ <= TAU) {
                    int slot = atomicAdd(&s_nflag, 1); // cap 512 == positions/block
                    s_flags[slot] = hw0 + p;
                }
            }
        }

    // ---- result output: wave's 32 positions (same-wave s_arg, no barrier)
    {
        int p = lane & 31, gi = lane >> 5;
        int ac = s_arg[wid * 32 + p];
        const float* ev = embT + (size_t)ac * GDIM;
        float* rp = out_res + (size_t)b * 262144 + (size_t)grp * 65536 + hw0 + p;
#pragma unroll
        for (int it = 0; it < 32; ++it) {
            int g = it * 2 + gi;
            rp[(size_t)g * 1024] = ev[g] * 0.5f;
        }
    }

    __syncthreads();
    // ---- argmin output: block's 512 positions, one coalesced pass
    if (t < 512)
        out_arg[(size_t)b * 4096 + (size_t)grp * 1024 + half * 512 + t] =
            (float)s_arg[t];
    __syncthreads();   // out_arg done before fix may overwrite it

    // ---- exact f64 fix of this block's flagged positions (typ. 0-4)
    const int nf = s_nflag;
    for (int f = wid; f < nf; f += 16) {
        const int hwa = s_flags[f];
        // stage x-vector to LDS (lane = dim); same-wave RAW: fence lgkm
        s_fixx[wid][lane] =
            x[(size_t)b * 262144 + (size_t)grp * 65536 + (size_t)lane * 1024 + hwa];
        asm volatile("s_waitcnt lgkmcnt(0)" ::: "memory");

        double bd = DBL_MAX; int bk = 0;
        for (int m = 0; m < KCODES / 64; ++m) {
            const int k = lane + m * 64;
            const float* er = embT + (size_t)k * GDIM;
            double dot = 0.0;
#pragma unroll
            for (int g = 0; g < GDIM; g += 4) {
                float4 e4 = *(const float4*)(er + g);
                float4 xv = *(const float4*)&s_fixx[wid][g];   // broadcast read
                dot += (double)xv.x * (double)e4.x;
                dot += (double)xv.y * (double)e4.y;
                dot += (double)xv.z * (double)e4.z;
                dot += (double)xv.w * (double)e4.w;
            }
            double s = e2d[k] - 2.0 * dot;
            if (s < bd) { bd = s; bk = k; }            // ascending k per lane
        }
        for (int off = 32; off > 0; off >>= 1) {       // lexicographic (s, k)
            double od = __shfl_down(bd, off, 64);
            int    ok = __shfl_down(bk, off, 64);
            if (od < bd || (od == bd && ok < bk)) { bd = od; bk = ok; }
        }
        bk = __shfl(bk, 0, 64);

        if (lane == 0)
            out_arg[(size_t)b * 4096 + (size_t)grp * 1024 + hwa] = (float)bk;
        out_res[(size_t)b * 262144 + (size_t)grp * 65536 + (size_t)lane * 1024 + hwa] =
            embT[(size_t)bk * GDIM + lane] * 0.5f;
    }
}

extern "C" void kernel_launch(void* const* d_in, const int* in_sizes, int n_in,
                              void* d_out, int out_size, void* d_ws, size_t ws_size,
                              hipStream_t stream) {
    const float* x = (const float*)d_in[0];      // (64,256,32,32) f32
    const float* w = (const float*)d_in[1];      // (64,512) f32
    float* out_res = (float*)d_out;              // 16777216 floats
    float* out_arg = (float*)d_out + 16777216;   // 262144 floats

    float*    embT   = (float*)d_ws;
    float*    e2     = embT + 32768;
    double*   e2d    = (double*)((char*)d_ws + (size_t)33280 * 4);
    short*    emb_hi = (short*)((float*)d_ws + 34304);
    short*    emb_lo = (short*)((float*)d_ws + 50688);

    prep_kernel<<<128, 256, 0, stream>>>(w, embT, e2, e2d, emb_hi, emb_lo);
    vq_kernel<<<512, 1024, 0, stream>>>(x, embT, e2, e2d, emb_hi, emb_lo,
                                        out_res, out_arg);
}

// Round 3
// 218.979 us; speedup vs baseline: 1.5058x; 1.1352x over previous
//
#include <hip/hip_runtime.h>
#include <float.h>

#define KCODES 512
#define GDIM 64
#define TAU 4.0e-3f   // pass-A worst err ~1e-3 (split-bf16, -2-folded); ~800 flags total, exact f64 fix

typedef __attribute__((ext_vector_type(8))) short short8;   // 8 bf16 = 4 VGPR
typedef __attribute__((ext_vector_type(4))) float floatx4;  // MFMA C/D

// ---- workspace layout (float-index units) ----
// embT   f32[512*64]     [0, 32768)        original w, code-major
// e2     f32[512]        [32768, 33280)
// e2d    f64[512]        [33280, 34304)    (byte 133120, 8-aligned)
// emb_hi bf16[512*64]    [34304, 50688)    split of (-2*w), code-major
// emb_lo bf16[512*64]    [50688, 67072)

__device__ __forceinline__ void bf16split(float x, short& hi, short& lo) {
    unsigned u = __float_as_uint(x);
    unsigned h = (u + 0x7fffu + ((u >> 16) & 1u)) >> 16;   // RNE to bf16
    hi = (short)h;
    float hf = __uint_as_float(h << 16);
    float l = x - hf;                                      // exact in f32
    unsigned ul = __float_as_uint(l);
    lo = (short)((ul + 0x7fffu + ((ul >> 16) & 1u)) >> 16);
}

__device__ __forceinline__ void gload_lds16(const void* g, void* l) {
    __builtin_amdgcn_global_load_lds(
        (const __attribute__((address_space(1))) void*)g,
        (__attribute__((address_space(3))) void*)l, 16, 0, 0);
}

// 128 blocks x 256 = 512 waves: wave k preps code k (lane = dim g).
// emb_hi/lo store split of (-2*w): exact x(-2) scaling folds the -2 into the
// MFMA so the epilogue has no per-candidate fma (C is preloaded with e2).
__launch_bounds__(256)
__global__ void prep_kernel(const float* __restrict__ w,
                            float* __restrict__ embT,
                            float* __restrict__ e2,
                            double* __restrict__ e2d,
                            short* __restrict__ emb_hi,
                            short* __restrict__ emb_lo) {
    int t = blockIdx.x * 256 + threadIdx.x;   // 0..32767
    int k = t >> 6;                            // code (wave-uniform)
    int g = t & 63;                            // dim  (lane)
    float v = w[(size_t)g * KCODES + k];
    embT[(size_t)k * GDIM + g] = v;            // lane-contiguous store
    short h, l; bf16split(-2.0f * v, h, l);
    emb_hi[(size_t)k * GDIM + g] = h;
    emb_lo[(size_t)k * GDIM + g] = l;
    float s = v * v;
    double sd = (double)v * (double)v;
#pragma unroll
    for (int off = 32; off > 0; off >>= 1) {
        s  += __shfl_xor(s, off, 64);
        sd += __shfl_xor(sd, off, 64);
    }
    if (g == 0) { e2[k] = s; e2d[k] = sd; }
}

// Fused pass A + exact fix.  2048 blocks x 256 threads (4 waves, 4 blocks/CU:
// the round-1 loop shape that measured VGPR=76, no spill).  Block = 128
// positions; wave = 32 positions (2 m-tiles).  512 codes in 8 chunks of 64,
// double-buffered via global_load_lds DMA with XOR-granule swizzle applied on
// the pre-swizzled GLOBAL source (dest stays linear — both-sides rule).
// Codebook = -2w (split bf16); MFMA C preloaded with e2  =>  s = acc directly.
// best/sec: fminf + fmed3 (median{best_old, sec, s} == new second-min).
// Near-ties (sec-best<=TAU) -> LDS flag list; block tail reranks them in f64
// (lexicographic (s,k)) and overwrites out_arg/out_res — no extra dispatch.
__launch_bounds__(256, 1)
__global__ void vq_kernel(const float* __restrict__ x,
                          const float* __restrict__ embT,
                          const float* __restrict__ e2,
                          const double* __restrict__ e2d,
                          const short* __restrict__ emb_hi,
                          const short* __restrict__ emb_lo,
                          float* __restrict__ out_res,
                          float* __restrict__ out_arg) {
    __shared__ short s_hi[2][64 * 64];
    __shared__ short s_lo[2][64 * 64];
    __shared__ float s_e2[512];
    __shared__ int   s_arg[128];
    __shared__ float s_fixx[4][64];
    __shared__ int   s_flags[128];
    __shared__ int   s_nflag;

    const int t = threadIdx.x;
    const int wid = t >> 6;
    const int lane = t & 63;
    const int q = lane >> 4;          // quad
    const int c = lane & 15;          // col within tile
    const int blk = blockIdx.x;
    const int grp = blk >> 9;                          // 512 blocks per group
    const int posbase = ((blk & 511) << 7) + wid * 32; // wave's 32 positions
    const int b = posbase >> 10;
    const int hwb = posbase & 1023;

    if (t == 0) s_nflag = 0;

    // DMA geometry: wave wid owns LDS shorts [wid*1024, +1024) = chunk rows
    // wid*16..wid*16+16.  Instr0 rows rA=wid*16+(lane>>3), instr1 rB=rA+8
    // (same low-3 bits -> same swizzled granule uA).
    const int rA = wid * 16 + (lane >> 3);
    const int rB = rA + 8;
    const int uA = (lane & 7) ^ (lane >> 3);
    const int srcA = rA * 64 + uA * 8;   // element offset within chunk
    const int srcB = rB * 64 + uA * 8;

#define PREFETCH(CH, BUF)                                                      \
    {                                                                          \
        const short* gh_ = emb_hi + (size_t)(CH) * 4096;                       \
        const short* gl_ = emb_lo + (size_t)(CH) * 4096;                       \
        gload_lds16(gh_ + srcA, &s_hi[BUF][wid * 1024]);                       \
        gload_lds16(gh_ + srcB, &s_hi[BUF][wid * 1024 + 512]);                 \
        gload_lds16(gl_ + srcA, &s_lo[BUF][wid * 1024]);                       \
        gload_lds16(gl_ + srcB, &s_lo[BUF][wid * 1024 + 512]);                 \
    }

    // issue chunk-0 DMA first; e2 stage + A-frag loads below overlap it
    PREFETCH(0, 0);
    s_e2[t] = e2[t];
    s_e2[t + 256] = e2[t + 256];

    const float* xbase = x + (size_t)b * 262144 + (size_t)grp * 65536 + hwb;

    // A fragments: [mt][kt], hi and lo. 8 strided dwords each, split to bf16.
    short8 ahi[2][2], alo[2][2];
#pragma unroll
    for (int mt = 0; mt < 2; ++mt)
#pragma unroll
        for (int kt = 0; kt < 2; ++kt) {
#pragma unroll
            for (int j = 0; j < 8; ++j) {
                float xv = xbase[(kt * 32 + q * 8 + j) * 1024 + mt * 16 + c];
                short h, l; bf16split(xv, h, l);
                ahi[mt][kt][j] = h; alo[mt][kt][j] = l;
            }
        }

    float best[2][4], sec[2][4]; int arg[2][4];
#pragma unroll
    for (int mt = 0; mt < 2; ++mt)
#pragma unroll
        for (int r = 0; r < 4; ++r) { best[mt][r] = FLT_MAX; sec[mt][r] = FLT_MAX; arg[mt][r] = 0; }

    const int p8 = (q ^ (c & 7)) << 3;   // swizzled read granule (shorts)

    __syncthreads();                      // drains chunk-0 DMA + e2 stage

    int cur = 0;
    for (int ch = 0; ch < 8; ++ch) {
        if (ch < 7) PREFETCH(ch + 1, cur ^ 1);   // in flight across MFMA block
        const int C0 = ch * 64;

#pragma unroll
        for (int nt = 0; nt < 4; ++nt) {
            const int o = (nt * 16 + c) * 64 + p8;     // (r&7)==(c&7) since 16|nt*16
            short8 bh0 = *(const short8*)&s_hi[cur][o];
            short8 bh1 = *(const short8*)&s_hi[cur][o ^ 32];   // granule q+4
            short8 bl0 = *(const short8*)&s_lo[cur][o];
            short8 bl1 = *(const short8*)&s_lo[cur][o ^ 32];
            const float se2 = s_e2[C0 + nt * 16 + c];
            const int   n   = C0 + nt * 16 + c;
#pragma unroll
            for (int mt = 0; mt < 2; ++mt) {
                floatx4 a4 = (floatx4){se2, se2, se2, se2};   // C = e2 (codebook = -2w)
                a4 = __builtin_amdgcn_mfma_f32_16x16x32_bf16(alo[mt][0], bh0, a4, 0, 0, 0);
                a4 = __builtin_amdgcn_mfma_f32_16x16x32_bf16(ahi[mt][0], bl0, a4, 0, 0, 0);
                a4 = __builtin_amdgcn_mfma_f32_16x16x32_bf16(ahi[mt][0], bh0, a4, 0, 0, 0);
                a4 = __builtin_amdgcn_mfma_f32_16x16x32_bf16(alo[mt][1], bh1, a4, 0, 0, 0);
                a4 = __builtin_amdgcn_mfma_f32_16x16x32_bf16(ahi[mt][1], bl1, a4, 0, 0, 0);
                a4 = __builtin_amdgcn_mfma_f32_16x16x32_bf16(ahi[mt][1], bh1, a4, 0, 0, 0);
                // epilogue: s = a4[r]; 4 VALU per candidate (min/cmp/cndmask/med3)
#pragma unroll
                for (int r = 0; r < 4; ++r) {
                    float s = a4[r];
                    float bo = best[mt][r];
                    best[mt][r] = fminf(bo, s);
                    arg[mt][r]  = (s < bo) ? n : arg[mt][r];
                    sec[mt][r]  = __builtin_amdgcn_fmed3f(bo, sec[mt][r], s);
                }
            }
        }

        // single barrier/chunk: separates this chunk's reads of buf[cur] from
        // next iter's DMA into buf[cur], and completes DMA into buf[cur^1].
        __syncthreads();
        cur ^= 1;
    }

    // ---- cross-lane merge over the 16 cols; record args + near-tie flags
#pragma unroll
    for (int mt = 0; mt < 2; ++mt)
#pragma unroll
        for (int r = 0; r < 4; ++r) {
            float b_ = best[mt][r], s_ = sec[mt][r]; int n_ = arg[mt][r];
#pragma unroll
            for (int sh = 1; sh < 16; sh <<= 1) {
                float ob = __shfl_xor(b_, sh, 64);
                float os = __shfl_xor(s_, sh, 64);
                int   on = __shfl_xor(n_, sh, 64);
                float bo = b_;
                b_ = fminf(bo, ob);
                n_ = (ob < bo) ? on : n_;
                s_ = fminf(fminf(s_, os), fmaxf(bo, ob));   // 2nd-min of union
            }
            if (c == 0) {
                int p = mt * 16 + q * 4 + r;           // 0..31 within wave
                s_arg[wid * 32 + p] = n_;
                if (s_ - b_ <= TAU) {
                    int slot = atomicAdd(&s_nflag, 1); // cap 128 == positions/block
                    s_flags[slot] = wid * 32 + p;      // block-local position
                }
            }
        }

    // ---- result output: wave's 32 positions (same-wave s_arg, no barrier)
    {
        int p = lane & 31, gi = lane >> 5;
        int ac = s_arg[wid * 32 + p];
        const float* ev = embT + (size_t)ac * GDIM;
        float* rp = out_res + (size_t)b * 262144 + (size_t)grp * 65536 + hwb + p;
#pragma unroll
        for (int it = 0; it < 32; ++it) {
            int g = it * 2 + gi;
            rp[(size_t)g * 1024] = ev[g] * 0.5f;
        }
    }

    __syncthreads();
    // ---- argmin output: block's 128 positions, one coalesced pass
    if (t < 128) {
        int bp = ((blk & 511) << 7) + t;
        out_arg[(size_t)(bp >> 10) * 4096 + (size_t)grp * 1024 + (bp & 1023)] =
            (float)s_arg[t];
    }
    __syncthreads();   // out_arg/out_res drained before fix may overwrite

    // ---- exact f64 fix of this block's flagged positions (typ. 0-1)
    const int nf = s_nflag;
    for (int f = wid; f < nf; f += 4) {
        const int hwa = s_flags[f];                 // block-local 0..127
        const int pos = ((blk & 511) << 7) + hwa;   // position within (grp) slab
        const int fb = pos >> 10;
        const int sidx = pos & 1023;
        // stage x-vector to LDS (lane = dim); same-wave RAW
        s_fixx[wid][lane] =
            x[(size_t)fb * 262144 + (size_t)grp * 65536 + (size_t)lane * 1024 + sidx];
        asm volatile("s_waitcnt lgkmcnt(0)" ::: "memory");

        double bd = DBL_MAX; int bk = 0;
        for (int m = 0; m < KCODES / 64; ++m) {
            const int k = lane + m * 64;
            const float* er = embT + (size_t)k * GDIM;
            double dot = 0.0;
#pragma unroll
            for (int g = 0; g < GDIM; g += 4) {
                float4 e4 = *(const float4*)(er + g);
                float4 xv = *(const float4*)&s_fixx[wid][g];   // broadcast read
                dot += (double)xv.x * (double)e4.x;
                dot += (double)xv.y * (double)e4.y;
                dot += (double)xv.z * (double)e4.z;
                dot += (double)xv.w * (double)e4.w;
            }
            double s = e2d[k] - 2.0 * dot;
            if (s < bd) { bd = s; bk = k; }            // ascending k per lane
        }
        for (int off = 32; off > 0; off >>= 1) {       // lexicographic (s, k)
            double od = __shfl_down(bd, off, 64);
            int    ok = __shfl_down(bk, off, 64);
            if (od < bd || (od == bd && ok < bk)) { bd = od; bk = ok; }
        }
        bk = __shfl(bk, 0, 64);

        if (lane == 0)
            out_arg[(size_t)fb * 4096 + (size_t)grp * 1024 + sidx] = (float)bk;
        out_res[(size_t)fb * 262144 + (size_t)grp * 65536 + (size_t)lane * 1024 + sidx] =
            embT[(size_t)bk * GDIM + lane] * 0.5f;
    }
#undef PREFETCH
}

extern "C" void kernel_launch(void* const* d_in, const int* in_sizes, int n_in,
                              void* d_out, int out_size, void* d_ws, size_t ws_size,
                              hipStream_t stream) {
    const float* x = (const float*)d_in[0];      // (64,256,32,32) f32
    const float* w = (const float*)d_in[1];      // (64,512) f32
    float* out_res = (float*)d_out;              // 16777216 floats
    float* out_arg = (float*)d_out + 16777216;   // 262144 floats

    float*    embT   = (float*)d_ws;
    float*    e2     = embT + 32768;
    double*   e2d    = (double*)((char*)d_ws + (size_t)33280 * 4);
    short*    emb_hi = (short*)((float*)d_ws + 34304);
    short*    emb_lo = (short*)((float*)d_ws + 50688);

    prep_kernel<<<128, 256, 0, stream>>>(w, embT, e2, e2d, emb_hi, emb_lo);
    vq_kernel<<<2048, 256, 0, stream>>>(x, embT, e2, e2d, emb_hi, emb_lo,
                                        out_res, out_arg);
}